// Round 1
// baseline (1327.982 us; speedup 1.0000x reference)
//
#include <hip/hip_runtime.h>
#include <hip/hip_bf16.h>
#include <stdint.h>

// Problem constants
#define L3D 3
#define BD 2
#define CD 2048
#define HW 3600
#define CH 256
#define HWP 3712   // 29 * 128, padded hw for 128-tiles
#define KD 6144    // L3D * CD, exact multiple of 32
#define SP 3712    // padded support dim (K of PV gemm, cols of red/attn)

typedef __attribute__((ext_vector_type(8))) short short8;
typedef __attribute__((ext_vector_type(4))) float f32x4;

__device__ __forceinline__ short f2bf(float v) {
  uint32_t x = __float_as_uint(v);
  uint32_t r = (x + 0x7FFFu + ((x >> 16) & 1u)) >> 16;   // RNE
  return (short)(r & 0xFFFFu);
}

__device__ __forceinline__ void load_lds16(const void* g, void* l) {
  __builtin_amdgcn_global_load_lds(
      (const __attribute__((address_space(1))) void*)g,
      (__attribute__((address_space(3))) void*)l, 16, 0, 0);
}

// ---------------- Kernel 1: inverse channel-L2-norm per (l,b,q) ----------------
// grid (ceil(HW/64), L*B), block 256 = 64 q-positions x 4 channel-parts
__global__ __launch_bounds__(256) void norm_k(const float* __restrict__ x,
                                              float* __restrict__ invn) {
  const int lb = blockIdx.y;
  const int tid = threadIdx.x;
  const int q = blockIdx.x * 64 + (tid & 63);
  const int part = tid >> 6;
  float s0 = 0.f, s1 = 0.f, s2 = 0.f, s3 = 0.f;
  if (q < HW) {
    const float* p = x + (size_t)lb * CD * HW + (size_t)part * 512 * HW + q;
    for (int c = 0; c < 512; c += 4) {
      float v0 = p[(size_t)(c + 0) * HW];
      float v1 = p[(size_t)(c + 1) * HW];
      float v2 = p[(size_t)(c + 2) * HW];
      float v3 = p[(size_t)(c + 3) * HW];
      s0 += v0 * v0; s1 += v1 * v1; s2 += v2 * v2; s3 += v3 * v3;
    }
  }
  __shared__ float buf[256];
  buf[tid] = (s0 + s1) + (s2 + s3);
  __syncthreads();
  if (tid < 64 && q < HW) {
    float t = buf[tid] + buf[tid + 64] + buf[tid + 128] + buf[tid + 192];
    invn[(size_t)lb * HW + q] = 1.f / fmaxf(sqrtf(t), 1e-12f);
  }
}

// ------ Kernel 2: normalize + transpose + cast bf16  [lb][c][q] -> [b][q][l*CD+c] ------
// grid (57 q-tiles, 32 c-tiles, L*B), block 256. usew: fold corr_weight[l]*TEMP into A side.
__global__ __launch_bounds__(256) void nt_k(const float* __restrict__ x,
                                            const float* __restrict__ invn,
                                            const float* __restrict__ cw,
                                            __hip_bfloat16* __restrict__ dst,
                                            int usew) {
  const int lb = blockIdx.z;
  const int l = lb / BD;
  const int b = lb % BD;
  const int qt = blockIdx.x * 64;
  const int ct = blockIdx.y * 64;
  const int tid = threadIdx.x;
  __shared__ float tile[64][65];

  const int tx = tid & 63, ty = tid >> 6;
  const float* px = x + ((size_t)lb * CD + ct) * HW;
  const int q = qt + tx;
#pragma unroll
  for (int r = 0; r < 16; r++) {
    int cl = r * 4 + ty;
    tile[cl][tx] = (q < HW) ? px[(size_t)cl * HW + q] : 0.f;
  }
  __syncthreads();

  const float scale = usew ? (cw[l] * 20.0f) : 1.0f;
  const int wx = tid & 7, wy = tid >> 3;
#pragma unroll
  for (int it = 0; it < 2; it++) {
    int qrow = wy + it * 32;
    int qq = qt + qrow;
    if (qq < HW) {
      float iv = invn[(size_t)lb * HW + qq] * scale;
      short8 pack;
#pragma unroll
      for (int j = 0; j < 8; j++)
        pack[j] = f2bf(tile[wx * 8 + j][qrow] * iv);
      *reinterpret_cast<short8*>(
          (__hip_bfloat16*)dst + ((size_t)b * HWP + qq) * KD + (size_t)l * CD + ct + wx * 8) = pack;
    }
  }
}

// ---------------- Kernel 3: main GEMM  red[b][q][s] = An[b][q][:] . Bn[b][s][:] ----------------
// m97 structure: 128x128 tile, BK=32, 4 waves of 64x64, global_load_lds width 16.
__global__ __launch_bounds__(256, 2) void gemm_main(const __hip_bfloat16* __restrict__ A,
                                                    const __hip_bfloat16* __restrict__ B,
                                                    float* __restrict__ C) {
  const int bz = blockIdx.z;
  const int m0 = blockIdx.y * 128;
  const int n0 = blockIdx.x * 128;
  const int tid = threadIdx.x;
  const int lane = tid & 63;
  const int wv = tid >> 6;

  __shared__ __hip_bfloat16 lA[128 * 32];
  __shared__ __hip_bfloat16 lB[128 * 32];

  const __hip_bfloat16* gA = A + (size_t)bz * HWP * KD;
  const __hip_bfloat16* gB = B + (size_t)bz * HWP * KD;

  const int r0 = tid >> 2;            // staging row (i=0), +64 for i=1
  const int kc = (tid & 3) * 8;       // staging k-offset (elements)
  const int wb = (tid & ~63) * 8;     // wave-uniform LDS element base

  const int wr = (wv >> 1) * 64;
  const int wc = (wv & 1) * 64;
  const int ml = lane & 15;
  const int kq = (lane >> 4) * 8;

  f32x4 acc[4][4];
#pragma unroll
  for (int i = 0; i < 4; i++)
#pragma unroll
    for (int j = 0; j < 4; j++) acc[i][j] = (f32x4){0.f, 0.f, 0.f, 0.f};

  for (int k0 = 0; k0 < KD; k0 += 32) {
    const __hip_bfloat16* pa0 = gA + (size_t)(m0 + r0) * KD + k0 + kc;
    const __hip_bfloat16* pb0 = gB + (size_t)(n0 + r0) * KD + k0 + kc;
    load_lds16(pa0, &lA[wb]);
    load_lds16(pa0 + (size_t)64 * KD, &lA[wb + 2048]);
    load_lds16(pb0, &lB[wb]);
    load_lds16(pb0 + (size_t)64 * KD, &lB[wb + 2048]);
    __syncthreads();

    short8 af[4], bfr[4];
#pragma unroll
    for (int t = 0; t < 4; t++) {
      af[t]  = *reinterpret_cast<const short8*>(&lA[(wr + t * 16 + ml) * 32 + kq]);
      bfr[t] = *reinterpret_cast<const short8*>(&lB[(wc + t * 16 + ml) * 32 + kq]);
    }
#pragma unroll
    for (int mt = 0; mt < 4; mt++)
#pragma unroll
      for (int nt = 0; nt < 4; nt++)
        acc[mt][nt] = __builtin_amdgcn_mfma_f32_16x16x32_bf16(af[mt], bfr[nt], acc[mt][nt], 0, 0, 0);
    __syncthreads();
  }

  float* oc = C + (size_t)bz * HWP * SP;
  const int rq = (lane >> 4) * 4;
  const int cl = lane & 15;
#pragma unroll
  for (int mt = 0; mt < 4; mt++) {
    const int rb = m0 + wr + mt * 16 + rq;
#pragma unroll
    for (int nt = 0; nt < 4; nt++) {
      const int col = n0 + wc + nt * 16 + cl;
      f32x4 v = acc[mt][nt];
#pragma unroll
      for (int r = 0; r < 4; r++) {
        const int rr = rb + r;
        if (rr < HW) oc[(size_t)rr * SP + col] = v[r];
      }
    }
  }
}

// ---------------- Kernel 4: row softmax, fp32 red -> bf16 attn (pad cols zeroed) ----------------
// grid (HW, B), block 256; 15 chunks of 256 cover SP=3712.
__global__ __launch_bounds__(256) void softmax_k(const float* __restrict__ red,
                                                 __hip_bfloat16* __restrict__ attn) {
  const int q = blockIdx.x;
  const int b = blockIdx.y;
  const float* row = red + ((size_t)b * HWP + q) * SP;
  __hip_bfloat16* orow = attn + ((size_t)b * HWP + q) * SP;
  const int tid = threadIdx.x;
  const int lane = tid & 63, wv = tid >> 6;

  float r[15];
  float mx = -3.4e38f;
#pragma unroll
  for (int i = 0; i < 15; i++) {
    int s = i * 256 + tid;
    float v = (s < HW) ? row[s] : -3.4e38f;
    r[i] = v;
    mx = fmaxf(mx, v);
  }
  for (int off = 32; off > 0; off >>= 1) mx = fmaxf(mx, __shfl_down(mx, off, 64));
  __shared__ float sm[4];
  if (lane == 0) sm[wv] = mx;
  __syncthreads();
  mx = fmaxf(fmaxf(sm[0], sm[1]), fmaxf(sm[2], sm[3]));

  float sum = 0.f;
#pragma unroll
  for (int i = 0; i < 15; i++) {
    int s = i * 256 + tid;
    float e = (s < HW) ? __expf(r[i] - mx) : 0.f;
    r[i] = e;
    sum += e;
  }
  for (int off = 32; off > 0; off >>= 1) sum += __shfl_down(sum, off, 64);
  __syncthreads();
  if (lane == 0) sm[wv] = sum;
  __syncthreads();
  const float inv = 1.f / (sm[0] + sm[1] + sm[2] + sm[3]);

#pragma unroll
  for (int i = 0; i < 15; i++) {
    int s = i * 256 + tid;
    if (s < SP) {
      short bv = f2bf(r[i] * inv);           // 0 for pad cols
      *reinterpret_cast<short*>(&orow[s]) = bv;
    }
  }
}

// ---------------- Kernel 2b: cast f_s -> bf16 v, pad s to SP with zeros ----------------
__global__ __launch_bounds__(256) void castv_k(const float* __restrict__ fs,
                                               __hip_bfloat16* __restrict__ vb) {
  const int idx = blockIdx.x * 256 + threadIdx.x;
  if (idx >= BD * CH * SP) return;
  const int s = idx % SP;
  const int bc = idx / SP;
  float v = (s < HW) ? fs[(size_t)bc * HW + s] : 0.f;
  *reinterpret_cast<short*>(&vb[idx]) = f2bf(v);
}

// ---------------- Kernel 5: PV GEMM + blend epilogue ----------------
// out[c][q] = sum_s vb[c][s] * attn[q][s]; M=256 (c), N=HWP (q), K=SP (s).
__global__ __launch_bounds__(256, 2) void pv_gemm(const __hip_bfloat16* __restrict__ A,
                                                  const __hip_bfloat16* __restrict__ B,
                                                  const float* __restrict__ fqin,
                                                  float* __restrict__ out) {
  const int bz = blockIdx.z;
  const int m0 = blockIdx.y * 128;   // c tile (2)
  const int n0 = blockIdx.x * 128;   // q tile (29)
  const int tid = threadIdx.x;
  const int lane = tid & 63;
  const int wv = tid >> 6;

  __shared__ __hip_bfloat16 lA[128 * 32];
  __shared__ __hip_bfloat16 lB[128 * 32];

  const __hip_bfloat16* gA = A + (size_t)bz * CH * SP;
  const __hip_bfloat16* gB = B + (size_t)bz * HWP * SP;

  const int r0 = tid >> 2;
  const int kc = (tid & 3) * 8;
  const int wb = (tid & ~63) * 8;

  const int wr = (wv >> 1) * 64;
  const int wc = (wv & 1) * 64;
  const int ml = lane & 15;
  const int kq = (lane >> 4) * 8;

  f32x4 acc[4][4];
#pragma unroll
  for (int i = 0; i < 4; i++)
#pragma unroll
    for (int j = 0; j < 4; j++) acc[i][j] = (f32x4){0.f, 0.f, 0.f, 0.f};

  for (int k0 = 0; k0 < SP; k0 += 32) {
    const __hip_bfloat16* pa0 = gA + (size_t)(m0 + r0) * SP + k0 + kc;
    const __hip_bfloat16* pb0 = gB + (size_t)(n0 + r0) * SP + k0 + kc;
    load_lds16(pa0, &lA[wb]);
    load_lds16(pa0 + (size_t)64 * SP, &lA[wb + 2048]);
    load_lds16(pb0, &lB[wb]);
    load_lds16(pb0 + (size_t)64 * SP, &lB[wb + 2048]);
    __syncthreads();

    short8 af[4], bfr[4];
#pragma unroll
    for (int t = 0; t < 4; t++) {
      af[t]  = *reinterpret_cast<const short8*>(&lA[(wr + t * 16 + ml) * 32 + kq]);
      bfr[t] = *reinterpret_cast<const short8*>(&lB[(wc + t * 16 + ml) * 32 + kq]);
    }
#pragma unroll
    for (int mt = 0; mt < 4; mt++)
#pragma unroll
      for (int nt = 0; nt < 4; nt++)
        acc[mt][nt] = __builtin_amdgcn_mfma_f32_16x16x32_bf16(af[mt], bfr[nt], acc[mt][nt], 0, 0, 0);
    __syncthreads();
  }

  const size_t obase = (size_t)bz * CH * HW;
  const size_t attoff = (size_t)BD * CH * HW;
  const int rq = (lane >> 4) * 4;
  const int cl = lane & 15;
#pragma unroll
  for (int mt = 0; mt < 4; mt++) {
    const int rb = m0 + wr + mt * 16 + rq;   // c
#pragma unroll
    for (int nt = 0; nt < 4; nt++) {
      const int col = n0 + wc + nt * 16 + cl;  // q
      if (col < HW) {
        f32x4 v = acc[mt][nt];
#pragma unroll
        for (int r = 0; r < 4; r++) {
          const int c = rb + r;
          size_t oi = obase + (size_t)c * HW + col;
          float att = v[r];
          out[oi] = (fqin[oi] + 0.3f * att) * (1.0f / 1.3f);
          out[attoff + oi] = att;
        }
      }
    }
  }
}

extern "C" void kernel_launch(void* const* d_in, const int* in_sizes, int n_in,
                              void* d_out, int out_size, void* d_ws, size_t ws_size,
                              hipStream_t stream) {
  const float* fqf = (const float*)d_in[0];   // [L,B,C,H,W]
  const float* fsf = (const float*)d_in[1];
  const float* f_q = (const float*)d_in[2];   // [B,CH,H,W]
  const float* f_s = (const float*)d_in[3];
  const float* cw  = (const float*)d_in[4];   // [L]
  float* out = (float*)d_out;

  // workspace carve (~293 MB): invq, invs, An, Bn, red; attn aliases An, vb aliases Bn
  char* w = (char*)d_ws;
  float* invq = (float*)w;  w += ((size_t)L3D * BD * HW * 4 + 255) & ~(size_t)255;
  float* invs = (float*)w;  w += ((size_t)L3D * BD * HW * 4 + 255) & ~(size_t)255;
  __hip_bfloat16* An = (__hip_bfloat16*)w;  w += (size_t)BD * HWP * KD * 2;
  __hip_bfloat16* Bn = (__hip_bfloat16*)w;  w += (size_t)BD * HWP * KD * 2;
  float* red = (float*)w;                   // [B][HWP][SP] fp32
  __hip_bfloat16* attn = (__hip_bfloat16*)An;  // dead after gemm_main
  __hip_bfloat16* vb   = (__hip_bfloat16*)Bn;  // dead after gemm_main
  (void)ws_size; (void)in_sizes; (void)n_in; (void)out_size;

  norm_k<<<dim3(57, L3D * BD), 256, 0, stream>>>(fqf, invq);
  norm_k<<<dim3(57, L3D * BD), 256, 0, stream>>>(fsf, invs);
  nt_k<<<dim3(57, 32, L3D * BD), 256, 0, stream>>>(fqf, invq, cw, An, 1);
  nt_k<<<dim3(57, 32, L3D * BD), 256, 0, stream>>>(fsf, invs, cw, Bn, 0);
  gemm_main<<<dim3(29, 29, BD), 256, 0, stream>>>(An, Bn, red);
  softmax_k<<<dim3(HW, BD), 256, 0, stream>>>(red, attn);
  castv_k<<<(BD * CH * SP + 255) / 256, 256, 0, stream>>>(f_s, vb);
  pv_gemm<<<dim3(29, 2, BD), 256, 0, stream>>>(vb, attn, f_q, out);
}

// Round 2
// 869.817 us; speedup vs baseline: 1.5267x; 1.5267x over previous
//
#include <hip/hip_runtime.h>
#include <hip/hip_bf16.h>
#include <stdint.h>

// Problem constants
#define L3D 3
#define BD 2
#define CD 2048
#define HW 3600
#define CH 256
#define HWP 3712   // 29 * 128, padded hw
#define KD 6144    // L3D * CD  (bytes per row in fp8 An/Bn)
#define SP 3712    // padded support dim
#define LB6 6      // L3D*BD
#define NPLANE 12  // both inputs' (l,b) planes

typedef __attribute__((ext_vector_type(8))) short short8;
typedef __attribute__((ext_vector_type(4))) float f32x4;
typedef __attribute__((ext_vector_type(2))) long i64x2;
typedef long i64;

__device__ __forceinline__ short f2bf(float v) {
  uint32_t x = __float_as_uint(v);
  uint32_t r = (x + 0x7FFFu + ((x >> 16) & 1u)) >> 16;   // RNE
  return (short)(r & 0xFFFFu);
}

__device__ __forceinline__ void load_lds16(const void* g, void* l) {
  __builtin_amdgcn_global_load_lds(
      (const __attribute__((address_space(1))) void*)g,
      (__attribute__((address_space(3))) void*)l, 16, 0, 0);
}

// ---------------- Norm stage 1: partial channel sums of squares ----------------
// partial[p][j][q], p in [0,4) (512-ch parts), j in [0,12): 0-5 fq planes, 6-11 fs
__global__ __launch_bounds__(256) void norm1_k(const float* __restrict__ fq,
                                               const float* __restrict__ fs,
                                               float* __restrict__ partial) {
  const int j = blockIdx.y;
  const int p = blockIdx.z;
  const float* x = (j < LB6) ? (fq + (size_t)j * CD * HW)
                             : (fs + (size_t)(j - LB6) * CD * HW);
  const int tid = threadIdx.x;
  const int q = blockIdx.x * 64 + (tid & 63);
  const int sub = tid >> 6;      // 4 subparts of 128 channels
  float s0 = 0.f, s1 = 0.f, s2 = 0.f, s3 = 0.f;
  if (q < HW) {
    const float* pp = x + ((size_t)p * 512 + (size_t)sub * 128) * HW + q;
    for (int c = 0; c < 128; c += 4) {
      float v0 = pp[(size_t)(c + 0) * HW];
      float v1 = pp[(size_t)(c + 1) * HW];
      float v2 = pp[(size_t)(c + 2) * HW];
      float v3 = pp[(size_t)(c + 3) * HW];
      s0 += v0 * v0; s1 += v1 * v1; s2 += v2 * v2; s3 += v3 * v3;
    }
  }
  __shared__ float buf[256];
  buf[tid] = (s0 + s1) + (s2 + s3);
  __syncthreads();
  if (tid < 64 && q < HW) {
    float t = buf[tid] + buf[tid + 64] + buf[tid + 128] + buf[tid + 192];
    partial[((size_t)p * NPLANE + j) * HW + q] = t;
  }
}

// ---------------- Norm stage 2: combine 4 partials -> 1/max(norm,eps) ----------------
__global__ __launch_bounds__(256) void norm2_k(const float* __restrict__ partial,
                                               float* __restrict__ invn) {
  const int idx = blockIdx.x * 256 + threadIdx.x;
  if (idx >= NPLANE * HW) return;
  const size_t st = (size_t)NPLANE * HW;
  float t = partial[idx] + partial[st + idx] + partial[2 * st + idx] + partial[3 * st + idx];
  invn[idx] = 1.f / fmaxf(sqrtf(t), 1e-12f);
}

// ------ Normalize + transpose + cast fp8 e4m3, k-block interleaved ------
// [lb][c][q] -> fp8 [b][q][perm(l*CD+c)]; within each 64-k group, byte position
// p holds k-block [0,4,1,5,2,6,3,7][p] so gemm can ds_read_b128 both k-halves.
__global__ __launch_bounds__(256) void nt_k(const float* __restrict__ x,
                                            const float* __restrict__ invn,
                                            const float* __restrict__ cw,
                                            uint8_t* __restrict__ dst,
                                            int usew) {
  const int lb = blockIdx.z;
  const int l = lb / BD;
  const int b = lb % BD;
  const int qt = blockIdx.x * 64;
  const int ct = blockIdx.y * 64;
  const int tid = threadIdx.x;
  __shared__ float tile[64][65];

  const int tx = tid & 63, ty = tid >> 6;
  const float* px = x + ((size_t)lb * CD + ct) * HW;
  const int q = qt + tx;
#pragma unroll
  for (int r = 0; r < 16; r++) {
    int cl = r * 4 + ty;
    tile[cl][tx] = (q < HW) ? px[(size_t)cl * HW + q] : 0.f;
  }
  __syncthreads();

  // scale by 32 to keep fp8 values in normal range; w_l folded into A side.
  const float scale = usew ? (cw[l] * 32.0f) : 32.0f;
  const int wx = tid & 7, wy = tid >> 3;
  const int pos = (wx & 3) * 2 + (wx >> 2);   // inverse k-block permutation
#pragma unroll
  for (int it = 0; it < 2; it++) {
    int qrow = wy + it * 32;
    int qq = qt + qrow;
    if (qq < HW) {
      float iv = invn[(size_t)lb * HW + qq] * scale;
      float v[8];
#pragma unroll
      for (int j = 0; j < 8; j++) v[j] = tile[wx * 8 + j][qrow] * iv;
      int lo = 0, hi = 0;
      lo = __builtin_amdgcn_cvt_pk_fp8_f32(v[0], v[1], lo, false);
      lo = __builtin_amdgcn_cvt_pk_fp8_f32(v[2], v[3], lo, true);
      hi = __builtin_amdgcn_cvt_pk_fp8_f32(v[4], v[5], hi, false);
      hi = __builtin_amdgcn_cvt_pk_fp8_f32(v[6], v[7], hi, true);
      int2 pk = make_int2(lo, hi);
      *reinterpret_cast<int2*>(dst + ((size_t)b * HWP + qq) * KD +
                               (size_t)l * CD + ct + pos * 8) = pk;
    }
  }
}

// ---------------- Main GEMM: fp8 e4m3, 128x128 tile, BK=64 ----------------
// red_bf16[b][q][s] = An[q][:] . Bn[s][:]  (values scaled by 1024; softmax rescales)
__global__ __launch_bounds__(256, 2) void gemm_main(const uint8_t* __restrict__ A,
                                                    const uint8_t* __restrict__ B,
                                                    __hip_bfloat16* __restrict__ C) {
  const int bz = blockIdx.z;
  const int m0 = blockIdx.y * 128;
  const int n0 = blockIdx.x * 128;
  const int tid = threadIdx.x;
  const int lane = tid & 63;
  const int wv = tid >> 6;

  __shared__ uint8_t lA[128 * 64];   // 8 KB
  __shared__ uint8_t lB[128 * 64];

  const uint8_t* gA = A + (size_t)bz * HWP * KD;
  const uint8_t* gB = B + (size_t)bz * HWP * KD;

  const int r0 = tid >> 2;            // staging row, +64 for second half
  const int kc = (tid & 3) * 16;      // staging k-offset (bytes)
  const int wb = (tid & ~63) * 16;    // wave-uniform LDS byte base

  const int wr = (wv >> 1) * 64;
  const int wc = (wv & 1) * 64;
  const int ml = lane & 15;
  const int kq = (lane >> 4) * 16;    // byte offset of this lane-group's 16B

  f32x4 acc[4][4];
#pragma unroll
  for (int i = 0; i < 4; i++)
#pragma unroll
    for (int j = 0; j < 4; j++) acc[i][j] = (f32x4){0.f, 0.f, 0.f, 0.f};

  for (int k0 = 0; k0 < KD; k0 += 64) {
    const uint8_t* pa0 = gA + (size_t)(m0 + r0) * KD + k0 + kc;
    const uint8_t* pb0 = gB + (size_t)(n0 + r0) * KD + k0 + kc;
    load_lds16(pa0, &lA[wb]);
    load_lds16(pa0 + (size_t)64 * KD, &lA[wb + 4096]);
    load_lds16(pb0, &lB[wb]);
    load_lds16(pb0 + (size_t)64 * KD, &lB[wb + 4096]);
    __syncthreads();

    i64 a0[4], a1[4], b0[4], b1[4];
#pragma unroll
    for (int t = 0; t < 4; t++) {
      i64x2 av = *reinterpret_cast<const i64x2*>(&lA[(wr + t * 16 + ml) * 64 + kq]);
      i64x2 bv = *reinterpret_cast<const i64x2*>(&lB[(wc + t * 16 + ml) * 64 + kq]);
      a0[t] = av[0]; a1[t] = av[1];
      b0[t] = bv[0]; b1[t] = bv[1];
    }
#pragma unroll
    for (int mt = 0; mt < 4; mt++)
#pragma unroll
      for (int nt = 0; nt < 4; nt++) {
        acc[mt][nt] = __builtin_amdgcn_mfma_f32_16x16x32_fp8_fp8(a0[mt], b0[nt], acc[mt][nt], 0, 0, 0);
        acc[mt][nt] = __builtin_amdgcn_mfma_f32_16x16x32_fp8_fp8(a1[mt], b1[nt], acc[mt][nt], 0, 0, 0);
      }
    __syncthreads();
  }

  __hip_bfloat16* oc = C + (size_t)bz * HWP * SP;
  const int rq = (lane >> 4) * 4;
  const int cl = lane & 15;
#pragma unroll
  for (int mt = 0; mt < 4; mt++) {
    const int rb = m0 + wr + mt * 16 + rq;
#pragma unroll
    for (int nt = 0; nt < 4; nt++) {
      const int col = n0 + wc + nt * 16 + cl;
      f32x4 v = acc[mt][nt];
#pragma unroll
      for (int r = 0; r < 4; r++) {
        const int rr = rb + r;
        if (rr < HW) *reinterpret_cast<short*>(&oc[(size_t)rr * SP + col]) = f2bf(v[r]);
      }
    }
  }
}

// ---------------- Row softmax: bf16 red -> bf16 attn (pad cols zeroed) ----------------
__global__ __launch_bounds__(256) void softmax_k(const __hip_bfloat16* __restrict__ red,
                                                 __hip_bfloat16* __restrict__ attn) {
  const int q = blockIdx.x;
  const int b = blockIdx.y;
  const __hip_bfloat16* row = red + ((size_t)b * HWP + q) * SP;
  __hip_bfloat16* orow = attn + ((size_t)b * HWP + q) * SP;
  const int tid = threadIdx.x;
  const int lane = tid & 63, wv = tid >> 6;
  const float SM = 20.0f / 1024.0f;   // undo the 32*32 fp8 range scaling, apply temp

  float r[15];
  float mx = -3.4e38f;
#pragma unroll
  for (int i = 0; i < 15; i++) {
    int s = i * 256 + tid;
    float v = (s < HW) ? __bfloat162float(row[s]) : -3.4e38f;
    r[i] = v;
    mx = fmaxf(mx, v);
  }
  for (int off = 32; off > 0; off >>= 1) mx = fmaxf(mx, __shfl_down(mx, off, 64));
  __shared__ float sm[4];
  if (lane == 0) sm[wv] = mx;
  __syncthreads();
  mx = fmaxf(fmaxf(sm[0], sm[1]), fmaxf(sm[2], sm[3]));

  float sum = 0.f;
#pragma unroll
  for (int i = 0; i < 15; i++) {
    int s = i * 256 + tid;
    float e = (s < HW) ? __expf((r[i] - mx) * SM) : 0.f;
    r[i] = e;
    sum += e;
  }
  for (int off = 32; off > 0; off >>= 1) sum += __shfl_down(sum, off, 64);
  __syncthreads();
  if (lane == 0) sm[wv] = sum;
  __syncthreads();
  const float inv = 1.f / (sm[0] + sm[1] + sm[2] + sm[3]);

#pragma unroll
  for (int i = 0; i < 15; i++) {
    int s = i * 256 + tid;
    if (s < SP) *reinterpret_cast<short*>(&orow[s]) = f2bf(r[i] * inv);
  }
}

// ---------------- Cast f_s -> bf16 v, zero-pad s to SP ----------------
__global__ __launch_bounds__(256) void castv_k(const float* __restrict__ fs,
                                               __hip_bfloat16* __restrict__ vb) {
  const int idx = blockIdx.x * 256 + threadIdx.x;
  if (idx >= BD * CH * SP) return;
  const int s = idx % SP;
  const int bc = idx / SP;
  float v = (s < HW) ? fs[(size_t)bc * HW + s] : 0.f;
  *reinterpret_cast<short*>(&vb[idx]) = f2bf(v);
}

// ---------------- PV GEMM + blend epilogue, 128(c) x 64(q) tiles ----------------
__global__ __launch_bounds__(256, 2) void pv_gemm(const __hip_bfloat16* __restrict__ A,
                                                  const __hip_bfloat16* __restrict__ B,
                                                  const float* __restrict__ fqin,
                                                  float* __restrict__ out) {
  const int bz = blockIdx.z;
  const int m0 = blockIdx.y * 128;   // c tile (2)
  const int n0 = blockIdx.x * 64;    // q tile (58)
  const int tid = threadIdx.x;
  const int lane = tid & 63;
  const int wv = tid >> 6;

  __shared__ __hip_bfloat16 lA[128 * 32];   // 8 KB
  __shared__ __hip_bfloat16 lB[64 * 32];    // 4 KB

  const __hip_bfloat16* gA = A + (size_t)bz * CH * SP;
  const __hip_bfloat16* gB = B + (size_t)bz * HWP * SP;

  const int r0 = tid >> 2;
  const int kc = (tid & 3) * 8;       // elements
  const int wb = (tid & ~63) * 8;     // wave-uniform LDS element base

  const int wr = (wv >> 1) * 64;      // m offset within tile
  const int wc = (wv & 1) * 32;       // n offset within tile
  const int ml = lane & 15;
  const int kq = (lane >> 4) * 8;

  f32x4 acc[4][2];
#pragma unroll
  for (int i = 0; i < 4; i++)
#pragma unroll
    for (int j = 0; j < 2; j++) acc[i][j] = (f32x4){0.f, 0.f, 0.f, 0.f};

  for (int k0 = 0; k0 < SP; k0 += 32) {
    const __hip_bfloat16* pa0 = gA + (size_t)(m0 + r0) * SP + k0 + kc;
    const __hip_bfloat16* pb0 = gB + (size_t)(n0 + r0) * SP + k0 + kc;
    load_lds16(pa0, &lA[wb]);
    load_lds16(pa0 + (size_t)64 * SP, &lA[wb + 2048]);
    load_lds16(pb0, &lB[wb]);   // 64 rows -> one 4KB stage by all 256 threads
    __syncthreads();

    short8 af[4], bfr[2];
#pragma unroll
    for (int t = 0; t < 4; t++)
      af[t] = *reinterpret_cast<const short8*>(&lA[(wr + t * 16 + ml) * 32 + kq]);
#pragma unroll
    for (int t = 0; t < 2; t++)
      bfr[t] = *reinterpret_cast<const short8*>(&lB[(wc + t * 16 + ml) * 32 + kq]);
#pragma unroll
    for (int mt = 0; mt < 4; mt++)
#pragma unroll
      for (int nt = 0; nt < 2; nt++)
        acc[mt][nt] = __builtin_amdgcn_mfma_f32_16x16x32_bf16(af[mt], bfr[nt], acc[mt][nt], 0, 0, 0);
    __syncthreads();
  }

  const size_t obase = (size_t)bz * CH * HW;
  const size_t attoff = (size_t)BD * CH * HW;
  const int rq = (lane >> 4) * 4;
  const int cl = lane & 15;
#pragma unroll
  for (int mt = 0; mt < 4; mt++) {
    const int rb = m0 + wr + mt * 16 + rq;   // c
#pragma unroll
    for (int nt = 0; nt < 2; nt++) {
      const int col = n0 + wc + nt * 16 + cl;  // q
      if (col < HW) {
        f32x4 v = acc[mt][nt];
#pragma unroll
        for (int r = 0; r < 4; r++) {
          const int c = rb + r;
          size_t oi = obase + (size_t)c * HW + col;
          float att = v[r];
          out[oi] = (fqin[oi] + 0.3f * att) * (1.0f / 1.3f);
          out[attoff + oi] = att;
        }
      }
    }
  }
}

extern "C" void kernel_launch(void* const* d_in, const int* in_sizes, int n_in,
                              void* d_out, int out_size, void* d_ws, size_t ws_size,
                              hipStream_t stream) {
  const float* fqf = (const float*)d_in[0];   // [L,B,C,H,W]
  const float* fsf = (const float*)d_in[1];
  const float* f_q = (const float*)d_in[2];   // [B,CH,H,W]
  const float* f_s = (const float*)d_in[3];
  const float* cw  = (const float*)d_in[4];   // [L]
  float* out = (float*)d_out;

  // workspace carve (~148 MB): partial, invn, An, Bn, red; attn+vb alias An/Bn
  char* w = (char*)d_ws;
  float* partial = (float*)w;  w += ((size_t)4 * NPLANE * HW * 4 + 255) & ~(size_t)255;
  float* invn = (float*)w;     w += ((size_t)NPLANE * HW * 4 + 255) & ~(size_t)255;
  uint8_t* An = (uint8_t*)w;   w += (size_t)BD * HWP * KD;        // 45.6 MB
  uint8_t* Bn = (uint8_t*)w;   w += (size_t)BD * HWP * KD;        // 45.6 MB
  __hip_bfloat16* red = (__hip_bfloat16*)w;                       // 55.1 MB
  __hip_bfloat16* attn = (__hip_bfloat16*)An;                     // 55.1 of 91.2 MB
  __hip_bfloat16* vb = (__hip_bfloat16*)(An + (size_t)BD * HWP * SP * 2);  // 3.8 MB
  float* invq = invn;
  float* invs = invn + (size_t)LB6 * HW;
  (void)ws_size; (void)in_sizes; (void)n_in; (void)out_size;

  norm1_k<<<dim3(57, NPLANE, 4), 256, 0, stream>>>(fqf, fsf, partial);
  norm2_k<<<(NPLANE * HW + 255) / 256, 256, 0, stream>>>(partial, invn);
  nt_k<<<dim3(57, 32, LB6), 256, 0, stream>>>(fqf, invq, cw, An, 1);
  nt_k<<<dim3(57, 32, LB6), 256, 0, stream>>>(fsf, invs, cw, Bn, 0);
  gemm_main<<<dim3(29, 29, BD), 256, 0, stream>>>(An, Bn, red);
  softmax_k<<<dim3(HW, BD), 256, 0, stream>>>(red, attn);
  castv_k<<<(BD * CH * SP + 255) / 256, 256, 0, stream>>>(f_s, vb);
  pv_gemm<<<dim3(58, 2, BD), 256, 0, stream>>>(vb, attn, f_q, out);
}

// Round 3
// 861.748 us; speedup vs baseline: 1.5410x; 1.0094x over previous
//
#include <hip/hip_runtime.h>
#include <hip/hip_bf16.h>
#include <stdint.h>

// Problem constants
#define L3D 3
#define BD 2
#define CD 2048
#define HW 3600
#define CH 256
#define HWP 3712   // 29 * 128, padded hw
#define KD 6144    // L3D * CD  (bytes per row in fp8 An/Bn)
#define SP 3712    // padded support dim
#define LB6 6      // L3D*BD
#define NPLANE 12  // both inputs' (l,b) planes

typedef __attribute__((ext_vector_type(8))) short short8;
typedef __attribute__((ext_vector_type(4))) float f32x4;
typedef __attribute__((ext_vector_type(4))) int i32x4;
typedef __attribute__((ext_vector_type(8))) int i32x8;

__device__ __forceinline__ short f2bf(float v) {
  uint32_t x = __float_as_uint(v);
  uint32_t r = (x + 0x7FFFu + ((x >> 16) & 1u)) >> 16;   // RNE
  return (short)(r & 0xFFFFu);
}

__device__ __forceinline__ void load_lds16(const void* g, void* l) {
  __builtin_amdgcn_global_load_lds(
      (const __attribute__((address_space(1))) void*)g,
      (__attribute__((address_space(3))) void*)l, 16, 0, 0);
}

// ---- Fused norm + normalize + transpose + fp8 cast, one kernel, 2 phases ----
// grid (57 q-tiles, 12 planes): planes 0-5 = fq -> An (w/ corr_weight), 6-11 = fs -> Bn.
// Phase 1: ssq over all 2048 channels for 64 q. Phase 2: re-read (LLC-hot),
// normalize, transpose to [b][q][l*CD+c] fp8 e4m3, PLAIN k order (K=128 MFMA layout).
__global__ __launch_bounds__(256) void fnt_k(const float* __restrict__ fq,
                                             const float* __restrict__ fs,
                                             const float* __restrict__ cw,
                                             uint8_t* __restrict__ An,
                                             uint8_t* __restrict__ Bn) {
  const int j = blockIdx.y;
  const int qt = blockIdx.x * 64;
  const bool isq = (j < LB6);
  const int lb = isq ? j : j - LB6;
  const int l = lb / BD, b = lb % BD;
  const float* x = (isq ? fq : fs) + (size_t)lb * CD * HW;
  uint8_t* dst = isq ? An : Bn;

  const int tid = threadIdx.x;
  const int tx = tid & 63, part = tid >> 6;
  const int q = qt + tx;

  // ---- phase 1: sum of squares (4 parts of 512 channels) ----
  float s0 = 0.f, s1 = 0.f, s2 = 0.f, s3 = 0.f;
  if (q < HW) {
    const float* p = x + (size_t)part * 512 * HW + q;
    for (int c = 0; c < 512; c += 4) {
      float v0 = p[(size_t)(c + 0) * HW];
      float v1 = p[(size_t)(c + 1) * HW];
      float v2 = p[(size_t)(c + 2) * HW];
      float v3 = p[(size_t)(c + 3) * HW];
      s0 += v0 * v0; s1 += v1 * v1; s2 += v2 * v2; s3 += v3 * v3;
    }
  }
  __shared__ float buf[256];
  __shared__ float ivs[64];
  buf[tid] = (s0 + s1) + (s2 + s3);
  __syncthreads();
  if (tid < 64) {
    float t = buf[tid] + buf[tid + 64] + buf[tid + 128] + buf[tid + 192];
    const float scale = isq ? (cw[l] * 32.0f) : 32.0f;  // fp8 range scaling
    ivs[tid] = (1.f / fmaxf(sqrtf(t), 1e-12f)) * scale;
  }

  // ---- phase 2: 32 c-tiles of 64x64, transpose + pack fp8 ----
  __shared__ float tile[64][65];
  const int wx = tid & 7, wy = tid >> 3;
  for (int ct = 0; ct < 32; ct++) {
    const float* px = x + (size_t)ct * 64 * HW;
    __syncthreads();   // tile free (also covers ivs write on first iter)
#pragma unroll
    for (int r = 0; r < 16; r++) {
      int cl = r * 4 + part;
      tile[cl][tx] = (q < HW) ? px[(size_t)cl * HW + q] : 0.f;
    }
    __syncthreads();
#pragma unroll
    for (int it = 0; it < 2; it++) {
      int qrow = wy + it * 32;
      int qq = qt + qrow;
      if (qq < HW) {
        float iv = ivs[qrow];
        float v[8];
#pragma unroll
        for (int jj = 0; jj < 8; jj++) v[jj] = tile[wx * 8 + jj][qrow] * iv;
        int lo = 0, hi = 0;
        lo = __builtin_amdgcn_cvt_pk_fp8_f32(v[0], v[1], lo, false);
        lo = __builtin_amdgcn_cvt_pk_fp8_f32(v[2], v[3], lo, true);
        hi = __builtin_amdgcn_cvt_pk_fp8_f32(v[4], v[5], hi, false);
        hi = __builtin_amdgcn_cvt_pk_fp8_f32(v[6], v[7], hi, true);
        int2 pk = make_int2(lo, hi);
        *reinterpret_cast<int2*>(dst + ((size_t)b * HWP + qq) * KD +
                                 (size_t)l * CD + ct * 64 + wx * 8) = pk;
      }
    }
  }
}

// ---------------- Main GEMM: MX-fp8 (scales=1.0), 128x128 tile, BK=128 ----------------
// LDS layout: row = 128 B = 8 chunks of 16 B; chunk c of row r lives at slot (c+r)&7
// -> fragment reads are 2-way (free) instead of 16-way conflicted.
__global__ __launch_bounds__(256, 2) void gemm_main(const uint8_t* __restrict__ A,
                                                    const uint8_t* __restrict__ B,
                                                    __hip_bfloat16* __restrict__ C) {
  const int bz = blockIdx.y;
  const int lin = blockIdx.x;            // 841 = 29*29, G=4 m-grouped for L2 reuse
  int m_t, n_t;
  if (lin < 812) { int g = lin / 116, r = lin % 116; m_t = g * 4 + (r & 3); n_t = r >> 2; }
  else           { m_t = 28; n_t = lin - 812; }
  const int m0 = m_t * 128, n0 = n_t * 128;
  const int tid = threadIdx.x;
  const int lane = tid & 63;
  const int wv = tid >> 6;

  __shared__ uint8_t lA[128 * 128];   // 16 KB
  __shared__ uint8_t lB[128 * 128];

  const uint8_t* gA = A + (size_t)bz * HWP * KD;
  const uint8_t* gB = B + (size_t)bz * HWP * KD;

  const int r_loc = tid >> 3;           // 0..31: row within 32-row staging call
  const int slot = tid & 7;             // LDS slot within row
  const int csw = (slot - r_loc) & 7;   // global chunk this lane fetches
  const int wavebase = (tid & ~63) * 16;

  const int wr = (wv >> 1) * 64;
  const int wc = (wv & 1) * 64;
  const int ml = lane & 15;
  const int kg = lane >> 4;             // k-group: 32 contiguous k bytes per lane

  f32x4 acc[4][4];
#pragma unroll
  for (int i = 0; i < 4; i++)
#pragma unroll
    for (int jj = 0; jj < 4; jj++) acc[i][jj] = (f32x4){0.f, 0.f, 0.f, 0.f};

  for (int k0 = 0; k0 < KD; k0 += 128) {
#pragma unroll
    for (int i = 0; i < 4; i++) {
      load_lds16(gA + (size_t)(m0 + i * 32 + r_loc) * KD + k0 + csw * 16,
                 &lA[i * 4096 + wavebase]);
      load_lds16(gB + (size_t)(n0 + i * 32 + r_loc) * KD + k0 + csw * 16,
                 &lB[i * 4096 + wavebase]);
    }
    __syncthreads();

    i32x8 af[4], bf[4];
#pragma unroll
    for (int t = 0; t < 4; t++) {
      {
        const int row = wr + t * 16 + ml;
        const int base = row << 7;
        i32x4 lo = *reinterpret_cast<const i32x4*>(&lA[base + (((kg * 2)     + row) & 7) * 16]);
        i32x4 hi = *reinterpret_cast<const i32x4*>(&lA[base + (((kg * 2 + 1) + row) & 7) * 16]);
        af[t] = __builtin_shufflevector(lo, hi, 0, 1, 2, 3, 4, 5, 6, 7);
      }
      {
        const int row = wc + t * 16 + ml;
        const int base = row << 7;
        i32x4 lo = *reinterpret_cast<const i32x4*>(&lB[base + (((kg * 2)     + row) & 7) * 16]);
        i32x4 hi = *reinterpret_cast<const i32x4*>(&lB[base + (((kg * 2 + 1) + row) & 7) * 16]);
        bf[t] = __builtin_shufflevector(lo, hi, 0, 1, 2, 3, 4, 5, 6, 7);
      }
    }
#pragma unroll
    for (int mt = 0; mt < 4; mt++)
#pragma unroll
      for (int nt = 0; nt < 4; nt++)
        acc[mt][nt] = __builtin_amdgcn_mfma_scale_f32_16x16x128_f8f6f4(
            af[mt], bf[nt], acc[mt][nt], 0, 0,   // cbsz=FP8, blgp=FP8
            0, 0x7F7F7F7F, 0, 0x7F7F7F7F);       // scales = 1.0
    __syncthreads();
  }

  __hip_bfloat16* oc = C + (size_t)bz * HWP * SP;
  const int rq = (lane >> 4) * 4;
  const int cl = lane & 15;
#pragma unroll
  for (int mt = 0; mt < 4; mt++) {
    const int rb = m0 + wr + mt * 16 + rq;
#pragma unroll
    for (int nt = 0; nt < 4; nt++) {
      const int col = n0 + wc + nt * 16 + cl;
      f32x4 v = acc[mt][nt];
#pragma unroll
      for (int r = 0; r < 4; r++) {
        const int rr = rb + r;
        if (rr < HW) *reinterpret_cast<short*>(&oc[(size_t)rr * SP + col]) = f2bf(v[r]);
      }
    }
  }
}

// ---------------- Row softmax: bf16 red -> bf16 attn (pad cols zeroed) ----------------
__global__ __launch_bounds__(256) void softmax_k(const __hip_bfloat16* __restrict__ red,
                                                 __hip_bfloat16* __restrict__ attn) {
  const int q = blockIdx.x;
  const int b = blockIdx.y;
  const __hip_bfloat16* row = red + ((size_t)b * HWP + q) * SP;
  __hip_bfloat16* orow = attn + ((size_t)b * HWP + q) * SP;
  const int tid = threadIdx.x;
  const int lane = tid & 63, wv = tid >> 6;
  const float SM = 20.0f / 1024.0f;   // undo 32*32 fp8 range scaling, apply temp

  float r[15];
  float mx = -3.4e38f;
#pragma unroll
  for (int i = 0; i < 15; i++) {
    int s = i * 256 + tid;
    float v = (s < HW) ? __bfloat162float(row[s]) : -3.4e38f;
    r[i] = v;
    mx = fmaxf(mx, v);
  }
  for (int off = 32; off > 0; off >>= 1) mx = fmaxf(mx, __shfl_down(mx, off, 64));
  __shared__ float sm[4];
  if (lane == 0) sm[wv] = mx;
  __syncthreads();
  mx = fmaxf(fmaxf(sm[0], sm[1]), fmaxf(sm[2], sm[3]));

  float sum = 0.f;
#pragma unroll
  for (int i = 0; i < 15; i++) {
    int s = i * 256 + tid;
    float e = (s < HW) ? __expf((r[i] - mx) * SM) : 0.f;
    r[i] = e;
    sum += e;
  }
  for (int off = 32; off > 0; off >>= 1) sum += __shfl_down(sum, off, 64);
  __syncthreads();
  if (lane == 0) sm[wv] = sum;
  __syncthreads();
  const float inv = 1.f / (sm[0] + sm[1] + sm[2] + sm[3]);

#pragma unroll
  for (int i = 0; i < 15; i++) {
    int s = i * 256 + tid;
    if (s < SP) *reinterpret_cast<short*>(&orow[s]) = f2bf(r[i] * inv);
  }
}

// ---------------- Cast f_s -> bf16 v, zero-pad s to SP ----------------
__global__ __launch_bounds__(256) void castv_k(const float* __restrict__ fs,
                                               __hip_bfloat16* __restrict__ vb) {
  const int idx = blockIdx.x * 256 + threadIdx.x;
  if (idx >= BD * CH * SP) return;
  const int s = idx % SP;
  const int bc = idx / SP;
  float v = (s < HW) ? fs[(size_t)bc * HW + s] : 0.f;
  *reinterpret_cast<short*>(&vb[idx]) = f2bf(v);
}

// ---------------- PV GEMM + blend epilogue, 128(c) x 64(q) tiles ----------------
__global__ __launch_bounds__(256, 2) void pv_gemm(const __hip_bfloat16* __restrict__ A,
                                                  const __hip_bfloat16* __restrict__ B,
                                                  const float* __restrict__ fqin,
                                                  float* __restrict__ out) {
  const int bz = blockIdx.z;
  const int m0 = blockIdx.y * 128;   // c tile (2)
  const int n0 = blockIdx.x * 64;    // q tile (58)
  const int tid = threadIdx.x;
  const int lane = tid & 63;
  const int wv = tid >> 6;

  __shared__ __hip_bfloat16 lA[128 * 32];   // 8 KB
  __shared__ __hip_bfloat16 lB[64 * 32];    // 4 KB

  const __hip_bfloat16* gA = A + (size_t)bz * CH * SP;
  const __hip_bfloat16* gB = B + (size_t)bz * HWP * SP;

  const int r0 = tid >> 2;
  const int kc = (tid & 3) * 8;       // elements
  const int wb = (tid & ~63) * 8;     // wave-uniform LDS element base

  const int wr = (wv >> 1) * 64;      // m offset within tile
  const int wc = (wv & 1) * 32;       // n offset within tile
  const int ml = lane & 15;
  const int kq = (lane >> 4) * 8;

  f32x4 acc[4][2];
#pragma unroll
  for (int i = 0; i < 4; i++)
#pragma unroll
    for (int jj = 0; jj < 2; jj++) acc[i][jj] = (f32x4){0.f, 0.f, 0.f, 0.f};

  for (int k0 = 0; k0 < SP; k0 += 32) {
    const __hip_bfloat16* pa0 = gA + (size_t)(m0 + r0) * SP + k0 + kc;
    const __hip_bfloat16* pb0 = gB + (size_t)(n0 + r0) * SP + k0 + kc;
    load_lds16(pa0, &lA[wb]);
    load_lds16(pa0 + (size_t)64 * SP, &lA[wb + 2048]);
    load_lds16(pb0, &lB[wb]);
    __syncthreads();

    short8 af[4], bfr[2];
#pragma unroll
    for (int t = 0; t < 4; t++)
      af[t] = *reinterpret_cast<const short8*>(&lA[(wr + t * 16 + ml) * 32 + kq]);
#pragma unroll
    for (int t = 0; t < 2; t++)
      bfr[t] = *reinterpret_cast<const short8*>(&lB[(wc + t * 16 + ml) * 32 + kq]);
#pragma unroll
    for (int mt = 0; mt < 4; mt++)
#pragma unroll
      for (int nt = 0; nt < 2; nt++)
        acc[mt][nt] = __builtin_amdgcn_mfma_f32_16x16x32_bf16(af[mt], bfr[nt], acc[mt][nt], 0, 0, 0);
    __syncthreads();
  }

  const size_t obase = (size_t)bz * CH * HW;
  const size_t attoff = (size_t)BD * CH * HW;
  const int rq = (lane >> 4) * 4;
  const int cl = lane & 15;
#pragma unroll
  for (int mt = 0; mt < 4; mt++) {
    const int rb = m0 + wr + mt * 16 + rq;   // c
#pragma unroll
    for (int nt = 0; nt < 2; nt++) {
      const int col = n0 + wc + nt * 16 + cl;  // q
      if (col < HW) {
        f32x4 v = acc[mt][nt];
#pragma unroll
        for (int r = 0; r < 4; r++) {
          const int c = rb + r;
          size_t oi = obase + (size_t)c * HW + col;
          float att = v[r];
          out[oi] = (fqin[oi] + 0.3f * att) * (1.0f / 1.3f);
          out[attoff + oi] = att;
        }
      }
    }
  }
}

extern "C" void kernel_launch(void* const* d_in, const int* in_sizes, int n_in,
                              void* d_out, int out_size, void* d_ws, size_t ws_size,
                              hipStream_t stream) {
  const float* fqf = (const float*)d_in[0];   // [L,B,C,H,W]
  const float* fsf = (const float*)d_in[1];
  const float* f_q = (const float*)d_in[2];   // [B,CH,H,W]
  const float* f_s = (const float*)d_in[3];
  const float* cw  = (const float*)d_in[4];   // [L]
  float* out = (float*)d_out;

  // workspace: An, Bn (fp8), red (bf16); attn + vb alias An/Bn after gemm
  char* w = (char*)d_ws;
  uint8_t* An = (uint8_t*)w;   w += (size_t)BD * HWP * KD;        // 45.6 MB
  uint8_t* Bn = (uint8_t*)w;   w += (size_t)BD * HWP * KD;        // 45.6 MB
  __hip_bfloat16* red = (__hip_bfloat16*)w;                       // 55.1 MB
  __hip_bfloat16* attn = (__hip_bfloat16*)An;                     // 55.1 of 91.2 MB
  __hip_bfloat16* vb = (__hip_bfloat16*)(An + (size_t)BD * HWP * SP * 2);  // 3.8 MB
  (void)ws_size; (void)in_sizes; (void)n_in; (void)out_size;

  fnt_k<<<dim3(57, NPLANE), 256, 0, stream>>>(fqf, fsf, cw, An, Bn);
  gemm_main<<<dim3(841, BD), 256, 0, stream>>>(An, Bn, red);
  softmax_k<<<dim3(HW, BD), 256, 0, stream>>>(red, attn);
  castv_k<<<(BD * CH * SP + 255) / 256, 256, 0, stream>>>(f_s, vb);
  pv_gemm<<<dim3(58, 2, BD), 256, 0, stream>>>(vb, attn, f_q, out);
}